// Round 4
// baseline (156.535 us; speedup 1.0000x reference)
//
#include <hip/hip_runtime.h>
#include <math.h>

constexpr int L = 32768;
constexpr int H = 256;
constexpr int P = 256;
constexpr int T = 64;        // scan chunk length
constexpr int NC = L / T;    // 512 chunks
constexpr int N1 = 2 * P;    // 512: X concat width, INTERLEAVED col = 2p+{0:re,1:im}
constexpr int LDEP = 130;    // epilogue LDS row stride (floats)

typedef __attribute__((ext_vector_type(8))) short short8;
typedef __attribute__((ext_vector_type(4))) float f32x4;

// ---------------- bf16 helpers (RNE) ----------------
__device__ __forceinline__ unsigned f2bf(float f) {
  unsigned u = __float_as_uint(f);
  return (u + 0x7FFFu + ((u >> 16) & 1u)) >> 16;
}
__device__ __forceinline__ float bf_lo(unsigned u) { return __uint_as_float(u << 16); }
__device__ __forceinline__ float bf_hi(unsigned u) { return __uint_as_float(u & 0xFFFF0000u); }

__device__ __forceinline__ void gload_lds16(const unsigned short* g, unsigned short* l) {
  __builtin_amdgcn_global_load_lds(
      (const __attribute__((address_space(1))) unsigned int*)(g),
      (__attribute__((address_space(3))) unsigned int*)(l), 16, 0, 0);
}

// Counted-vmcnt barrier: oldest needed gloads landed, deeper prefetches stay
// in flight. lgkmcnt(0) publishes ds_writes / completes ds_reads per wave.
#define KBAR(N) do { \
    asm volatile("s_waitcnt vmcnt(" #N ") lgkmcnt(0)" ::: "memory"); \
    __builtin_amdgcn_s_barrier(); \
    __builtin_amdgcn_sched_barrier(0); \
  } while (0)

// Pin VMEM issue order only (ALU/VALU/SALU/MFMA/DS may cross).
#define VMEM_FENCE() __builtin_amdgcn_sched_barrier(0x38F)

__device__ __forceinline__ void lambda_bar_of(const float* __restrict__ lam,
                                              const float* __restrict__ lstep,
                                              int p, float& lbr, float& lbi) {
  float lr = lam[2 * p], li = lam[2 * p + 1];
  float st = expf(lstep[p]);
  float ea = expf(lr * st);
  lbr = ea * cosf(li * st);
  lbi = ea * sinf(li * st);
}

// ---------------------------------------------------------------------------
// k_prep: Bcat (512 x 256 bf16), Ccat (256 x 512 bf16), pow (T x P fp32),
// PLUS sigt: sig converted to bf16 in FRAGMENT-MAJOR tile order:
//   sigt[panel][ks][c]*8shorts, panel=row/128, ks=k/32, chunk c in [0,512):
//   c -> row = 64*(c>>8) + 16*((c>>6)&3) + (c&15), kk = 8*((c>>4)&3).
// ---------------------------------------------------------------------------
__global__ __launch_bounds__(256) void k_prep(const float* __restrict__ sig,
                                              const float* __restrict__ lam,
                                              const float* __restrict__ lstep,
                                              const float* __restrict__ Bri,
                                              const float* __restrict__ Cri,
                                              unsigned short* __restrict__ Bcat,
                                              unsigned short* __restrict__ Ccat,
                                              float* __restrict__ powr,
                                              float* __restrict__ powi,
                                              unsigned short* __restrict__ sigt) {
  int idx = blockIdx.x * 256 + threadIdx.x;  // < 1327104
  if (idx < N1 * H) {
    int n = idx >> 8, k = idx & 255;
    int p = n >> 1, comp = n & 1;
    float lr = lam[2 * p], li = lam[2 * p + 1];
    float st = expf(lstep[p]);
    float ea = expf(lr * st);
    float lbr = ea * cosf(li * st), lbi = ea * sinf(li * st);
    float inv = 1.0f / (lr * lr + li * li);
    float nr = lbr - 1.0f;
    float fr = (nr * lr + lbi * li) * inv;
    float fi = (lbi * lr - nr * li) * inv;
    float br = Bri[2 * (p * H + k)], bi = Bri[2 * (p * H + k) + 1];
    float v = (comp == 0) ? (fr * br - fi * bi) : (fr * bi + fi * br);
    Bcat[idx] = (unsigned short)f2bf(v);
  } else if (idx < 2 * N1 * H) {
    int j = idx - N1 * H;
    int h = j >> 9, k2 = j & 511;
    int p = k2 >> 1;
    float v = ((k2 & 1) == 0) ? Cri[2 * (h * P + p)] : -Cri[2 * (h * P + p) + 1];
    Ccat[j] = (unsigned short)f2bf(v);
  } else if (idx < 2 * N1 * H + T * P) {
    int r = idx - 2 * N1 * H;  // < T*P
    int t = r >> 8, p = r & 255;
    float lr = lam[2 * p], li = lam[2 * p + 1];
    float st = expf(lstep[p]);
    float e = (float)(t + 1);
    float er = expf(e * lr * st);
    powr[r] = er * cosf(e * li * st);
    powi[r] = er * sinf(e * li * st);
  } else {
    int C = idx - (2 * N1 * H + T * P);   // < 1048576 (one 16B chunk each)
    int panel = C >> 12;                   // 4096 chunks per 128-row panel
    int ks = (C >> 9) & 7;
    int c = C & 511;
    int row = ((c >> 8) << 6) + (((c >> 6) & 3) << 4) + (c & 15);
    int kk = ((c >> 4) & 3) << 3;
    const float* s = sig + (size_t)(panel * 128 + row) * 256 + ks * 32 + kk;
    float4 a = *(const float4*)(s);
    float4 b = *(const float4*)(s + 4);
    uint4 w;
    w.x = f2bf(a.x) | (f2bf(a.y) << 16);
    w.y = f2bf(a.z) | (f2bf(a.w) << 16);
    w.z = f2bf(b.x) | (f2bf(b.y) << 16);
    w.w = f2bf(b.z) | (f2bf(b.w) << 16);
    *(uint4*)(sigt + (size_t)C * 8) = w;
  }
}

// ---------------------------------------------------------------------------
// GEMM1 fused: 128x128 tile (2 chunks). BOTH operands via global_load_lds,
// fragment-major, conflict-free. A: 3-deep ring; B: 2-deep. LDS = 40 KB.
// Counted vmcnt: steady barrier waits vmcnt(2) only.
// Epilogue: per-chunk LDS dump + in-block scan -> Xl + S (S transposed [p][NC]).
// grid (L/128, N1/128) = (256, 4).              [unchanged from round 3]
// ---------------------------------------------------------------------------
__global__ __launch_bounds__(256, 4) void k_gemm1s(const unsigned short* __restrict__ sigt,
                                                   const unsigned short* __restrict__ Bcat,
                                                   const float* __restrict__ lam,
                                                   const float* __restrict__ lstep,
                                                   unsigned short* __restrict__ Xl,
                                                   float* __restrict__ Sr,
                                                   float* __restrict__ Si) {
  constexpr int NIT = 8;   // K=256 / 32
  __shared__ __align__(16) char smem[40960];
  unsigned short* sA[3] = {(unsigned short*)smem, (unsigned short*)(smem + 8192),
                           (unsigned short*)(smem + 16384)};
  unsigned short* sB[2] = {(unsigned short*)(smem + 24576), (unsigned short*)(smem + 32768)};
  float* sEpi = (float*)smem;
  const int tid = threadIdx.x;
  const int lane = tid & 63;
  const int wave = tid >> 6;
  const int wc = (wave & 1) * 64;
  const int m0 = blockIdx.x * 128, n0 = blockIdx.y * 128;
  const int brow = ((tid >> 6) << 4) | (tid & 15);    // B staging source row
  const int bko = ((tid >> 4) & 3) * 8;               // B staging k-subgroup
  const int hb = (wave & 1) * 2048;                   // B half base (shorts)
  const int afb = (wave >> 1) * 256;                  // A frag chunk base
  const unsigned short* apan = sigt + (size_t)blockIdx.x * 32768;  // 8 ks * 4096 shorts
  f32x4 acc[4][4];
#pragma unroll
  for (int i = 0; i < 4; i++)
#pragma unroll
    for (int j = 0; j < 4; j++) acc[i][j] = (f32x4){0.f, 0.f, 0.f, 0.f};

#define ISSUE_A1(ks, buf) { \
    gload_lds16(apan + (ks) * 4096 + tid * 8, sA[buf] + tid * 8); \
    gload_lds16(apan + (ks) * 4096 + 2048 + tid * 8, sA[buf] + 2048 + tid * 8); }
#define ISSUE_B1(ks, buf) { \
    gload_lds16(Bcat + (size_t)(n0 + brow) * 256 + (ks) * 32 + bko, sB[buf] + tid * 8); \
    gload_lds16(Bcat + (size_t)(n0 + 64 + brow) * 256 + (ks) * 32 + bko, sB[buf] + 2048 + tid * 8); }

  // prologue: issue A0(2) B0(2) A1(2); wait B0 -> vmcnt(2) leaves A1 in flight
  ISSUE_A1(0, 0);
  VMEM_FENCE();
  ISSUE_B1(0, 0);
  VMEM_FENCE();
  ISSUE_A1(1, 1);
  VMEM_FENCE();
  KBAR(2);
#pragma unroll
  for (int it = 0; it < NIT; it++) {
    if (it + 1 < NIT) ISSUE_B1(it + 1, (it + 1) & 1);
    VMEM_FENCE();
    if (it + 2 < NIT) ISSUE_A1(it + 2, (it + 2) % 3);
    VMEM_FENCE();
    const unsigned short* sAc = sA[it % 3];
    const unsigned short* sBc = sB[it & 1];
    short8 af[4], bfr[4];
#pragma unroll
    for (int i = 0; i < 4; i++) af[i] = *(const short8*)(sAc + (afb + i * 64 + lane) * 8);
#pragma unroll
    for (int j = 0; j < 4; j++) bfr[j] = *(const short8*)(sBc + hb + (j * 64 + lane) * 8);
#pragma unroll
    for (int i = 0; i < 4; i++)
#pragma unroll
      for (int j = 0; j < 4; j++)
        acc[i][j] = __builtin_amdgcn_mfma_f32_16x16x32_bf16(af[i], bfr[j], acc[i][j], 0, 0, 0);
    if (it + 1 < NIT) {
      if (it + 2 < NIT) { KBAR(2); } else { KBAR(0); }
    }
  }
  __syncthreads();

  // ---- epilogue: per chunk-half: dump rows to LDS, scan, store ----
  const int crow = (lane >> 4) * 4, ccol = wc + (lane & 15);
#pragma unroll
  for (int half = 0; half < 2; half++) {
    if ((wave >> 1) == half) {
#pragma unroll
      for (int i = 0; i < 4; i++)
#pragma unroll
        for (int j = 0; j < 4; j++)
#pragma unroll
          for (int g = 0; g < 4; g++)
            sEpi[(crow + i * 16 + g) * LDEP + ccol + j * 16] = acc[i][j][g];
    }
    __syncthreads();
    if (tid < 64) {
      const int pl = tid;
      const int gp = (n0 >> 1) + pl;
      const int c = blockIdx.x * 2 + half;
      float lbr, lbi;
      lambda_bar_of(lam, lstep, gp, lbr, lbi);
      float xr = 0.f, xi = 0.f;
      const float* e = sEpi + 2 * pl;
      const size_t gbase = (size_t)(m0 + half * 64) * N1 + n0 + 2 * pl;
      for (int tb = 0; tb < T; tb += 8) {
        float2 v[8];
#pragma unroll
        for (int u = 0; u < 8; u++) v[u] = *(const float2*)(e + (tb + u) * LDEP);
        unsigned ov[8];
#pragma unroll
        for (int u = 0; u < 8; u++) {
          float nr = fmaf(lbr, xr, fmaf(-lbi, xi, v[u].x));
          float ni = fmaf(lbr, xi, fmaf(lbi, xr, v[u].y));
          xr = nr; xi = ni;
          ov[u] = f2bf(xr) | (f2bf(xi) << 16);
        }
#pragma unroll
        for (int u = 0; u < 8; u++)
          *(unsigned*)(Xl + gbase + (size_t)(tb + u) * N1) = ov[u];
      }
      Sr[(size_t)gp * NC + c] = xr;   // TRANSPOSED [p][NC]
      Si[(size_t)gp * NC + c] = xi;
    }
    __syncthreads();
  }
#undef ISSUE_A1
#undef ISSUE_B1
}

// ---------------------------------------------------------------------------
// Parallel carry scan: 256 blocks (one per p) x 64 threads.  [unchanged]
// ---------------------------------------------------------------------------
__global__ __launch_bounds__(64) void k_carry2(const float* __restrict__ lam,
                                               const float* __restrict__ lstep,
                                               const float* __restrict__ Sr,
                                               const float* __restrict__ Si,
                                               float* __restrict__ car, float* __restrict__ cai) {
  const int p = blockIdx.x;
  const int t = threadIdx.x;  // 0..63
  float lr = lam[2 * p], li = lam[2 * p + 1];
  float st = expf(lstep[p]);
  float eT = expf((float)T * lr * st);
  float lTr = eT * cosf((float)T * li * st);
  float lTi = eT * sinf((float)T * li * st);
  float vr[8], vi[8];
  {
    const float* srp = Sr + (size_t)p * NC + t * 8;
    const float* sip = Si + (size_t)p * NC + t * 8;
    float4 a0 = *(const float4*)(srp), a1 = *(const float4*)(srp + 4);
    float4 b0 = *(const float4*)(sip), b1 = *(const float4*)(sip + 4);
    vr[0] = a0.x; vr[1] = a0.y; vr[2] = a0.z; vr[3] = a0.w;
    vr[4] = a1.x; vr[5] = a1.y; vr[6] = a1.z; vr[7] = a1.w;
    vi[0] = b0.x; vi[1] = b0.y; vi[2] = b0.z; vi[3] = b0.w;
    vi[4] = b1.x; vi[5] = b1.y; vi[6] = b1.z; vi[7] = b1.w;
  }
  float Br = 0.f, Bi = 0.f;
#pragma unroll
  for (int u = 0; u < 8; u++) {
    float nr = fmaf(lTr, Br, fmaf(-lTi, Bi, vr[u]));
    float ni = fmaf(lTr, Bi, fmaf(lTi, Br, vi[u]));
    Br = nr; Bi = ni;
  }
  float e8 = expf(8.0f * (float)T * lr * st);
  float Ar = e8 * cosf(8.0f * (float)T * li * st);
  float Ai = e8 * sinf(8.0f * (float)T * li * st);
#pragma unroll
  for (int d = 1; d < 64; d <<= 1) {
    float Aor = __shfl_up(Ar, d), Aoi = __shfl_up(Ai, d);
    float Bor = __shfl_up(Br, d), Boi = __shfl_up(Bi, d);
    if (t >= d) {
      float nBr = Ar * Bor - Ai * Boi + Br;
      float nBi = Ar * Boi + Ai * Bor + Bi;
      float nAr = Aor * Ar - Aoi * Ai;
      float nAi = Aor * Ai + Aoi * Ar;
      Br = nBr; Bi = nBi; Ar = nAr; Ai = nAi;
    }
  }
  float cr = __shfl_up(Br, 1), ci = __shfl_up(Bi, 1);
  if (t == 0) { cr = 0.f; ci = 0.f; }
#pragma unroll
  for (int u = 0; u < 8; u++) {
    car[(t * 8 + u) * P + p] = cr;
    cai[(t * 8 + u) * P + p] = ci;
    float nr = fmaf(lTr, cr, fmaf(-lTi, ci, vr[u]));
    float ni = fmaf(lTr, ci, fmaf(lTi, cr, vi[u]));
    cr = nr; ci = ni;
  }
}

// ---------------------------------------------------------------------------
// k_fix: Xg = Xl + pow*carry, written bf16 in FRAGMENT-MAJOR order for gemm2:
//   Xg[panel=row/128][ks=col/32][c]*8shorts, c from (row&127, kk) per sigt map.
// Each thread: one row x 32 cols (64 B coalesced read, 4x16B writes).
// grid 2048 x 256.
// ---------------------------------------------------------------------------
__device__ __forceinline__ unsigned mix1(unsigned u, float pr, float pi, float cr, float ci) {
  float re = bf_lo(u) + (pr * cr - pi * ci);
  float im = bf_hi(u) + (pr * ci + pi * cr);
  return f2bf(re) | (f2bf(im) << 16);
}

__global__ __launch_bounds__(256) void k_fix(const unsigned short* __restrict__ Xl,
                                             const float* __restrict__ powr,
                                             const float* __restrict__ powi,
                                             const float* __restrict__ car,
                                             const float* __restrict__ cai,
                                             unsigned short* __restrict__ Xg) {
  int g = blockIdx.x * 256 + threadIdx.x;   // < L*16
  int row = g >> 4, seg = g & 15;
  int t = row & 63, cidx = row >> 6, rowp = row & 127, panel = row >> 7;
  int p0 = seg * 16;
  const unsigned short* xs = Xl + (size_t)row * N1 + seg * 32;
  uint4 x0 = *(const uint4*)(xs);
  uint4 x1 = *(const uint4*)(xs + 8);
  uint4 x2 = *(const uint4*)(xs + 16);
  uint4 x3 = *(const uint4*)(xs + 24);
  const float* prB = powr + t * P + p0;
  const float* piB = powi + t * P + p0;
  const float* crB = car + cidx * P + p0;
  const float* ciB = cai + cidx * P + p0;
  const int cb = ((rowp >> 6) << 8) | (((rowp >> 4) & 3) << 6) | (rowp & 15);
  unsigned short* xd = Xg + (size_t)panel * 65536 + (size_t)seg * 4096 + cb * 8;
#define FIXQ(XQ, q) { \
    float4 pr = *(const float4*)(prB + 4 * (q)); \
    float4 pi = *(const float4*)(piB + 4 * (q)); \
    float4 cr = *(const float4*)(crB + 4 * (q)); \
    float4 ci = *(const float4*)(ciB + 4 * (q)); \
    uint4 o; \
    o.x = mix1(XQ.x, pr.x, pi.x, cr.x, ci.x); \
    o.y = mix1(XQ.y, pr.y, pi.y, cr.y, ci.y); \
    o.z = mix1(XQ.z, pr.z, pi.z, cr.z, ci.z); \
    o.w = mix1(XQ.w, pr.w, pi.w, cr.w, ci.w); \
    *(uint4*)(xd + (q) * 128) = o; }
  FIXQ(x0, 0);
  FIXQ(x1, 1);
  FIXQ(x2, 2);
  FIXQ(x3, 3);
#undef FIXQ
}

// ---------------------------------------------------------------------------
// GEMM2 pure: 128x64 tile, grid (L/128, H/64) = (256, 4) -> 4 blocks/CU.
// BOTH operands via global_load_lds, fragment-major, conflict-free.
// A (Xg): 3-deep ring, 2 gloads/thread; B (Ccat): 2-deep, 1 gload/thread.
// LDS = 32 KB. Steady barrier waits vmcnt(2). Epilogue: + D*sig.
// ---------------------------------------------------------------------------
__global__ __launch_bounds__(256, 4) void k_gemm2p(const unsigned short* __restrict__ Xg,
                                                   const unsigned short* __restrict__ Ccat,
                                                   const float* __restrict__ sig,
                                                   const float* __restrict__ Dv,
                                                   float* __restrict__ out) {
  constexpr int NIT = 16;   // K=512 / 32
  __shared__ __align__(16) char smem[32768];
  unsigned short* sA[3] = {(unsigned short*)smem, (unsigned short*)(smem + 8192),
                           (unsigned short*)(smem + 16384)};
  unsigned short* sB[2] = {(unsigned short*)(smem + 24576), (unsigned short*)(smem + 28672)};
  const int tid = threadIdx.x;
  const int lane = tid & 63;
  const int wave = tid >> 6;
  const int m0 = blockIdx.x * 128, n0 = blockIdx.y * 64;
  const int brow = (((tid >> 6) & 3) << 4) | (tid & 15);  // B staging source row (0..63)
  const int bko = ((tid >> 4) & 3) * 8;                   // B staging k-subgroup
  const int afb = (wave >> 1) * 256;                      // A frag chunk base
  const int bfb = (wave & 1) * 2;                         // B frag chunk-group base
  const unsigned short* apan = Xg + (size_t)blockIdx.x * 65536;  // 16 ks * 4096 shorts
  f32x4 acc[4][2];
#pragma unroll
  for (int i = 0; i < 4; i++)
#pragma unroll
    for (int j = 0; j < 2; j++) acc[i][j] = (f32x4){0.f, 0.f, 0.f, 0.f};

#define ISSUE_A2(ks, buf) { \
    gload_lds16(apan + (ks) * 4096 + tid * 8, sA[buf] + tid * 8); \
    gload_lds16(apan + (ks) * 4096 + 2048 + tid * 8, sA[buf] + 2048 + tid * 8); }
#define ISSUE_B2(ks, buf) { \
    gload_lds16(Ccat + (size_t)(n0 + brow) * 512 + (ks) * 32 + bko, sB[buf] + tid * 8); }

  // prologue: A0(2) B0(1) A1(2); wait B0 -> vmcnt(2) leaves A1 in flight
  ISSUE_A2(0, 0);
  VMEM_FENCE();
  ISSUE_B2(0, 0);
  VMEM_FENCE();
  ISSUE_A2(1, 1);
  VMEM_FENCE();
  KBAR(2);
#pragma unroll
  for (int it = 0; it < NIT; it++) {
    if (it + 1 < NIT) ISSUE_B2(it + 1, (it + 1) & 1);
    VMEM_FENCE();
    if (it + 2 < NIT) ISSUE_A2(it + 2, (it + 2) % 3);
    VMEM_FENCE();
    const unsigned short* sAc = sA[it % 3];
    const unsigned short* sBc = sB[it & 1];
    short8 af[4], bfr[2];
#pragma unroll
    for (int i = 0; i < 4; i++) af[i] = *(const short8*)(sAc + (afb + i * 64 + lane) * 8);
#pragma unroll
    for (int j = 0; j < 2; j++) bfr[j] = *(const short8*)(sBc + ((bfb + j) * 64 + lane) * 8);
#pragma unroll
    for (int i = 0; i < 4; i++)
#pragma unroll
      for (int j = 0; j < 2; j++)
        acc[i][j] = __builtin_amdgcn_mfma_f32_16x16x32_bf16(af[i], bfr[j], acc[i][j], 0, 0, 0);
    if (it + 1 < NIT) {
      if (it + 2 < NIT) { KBAR(2); } else { KBAR(0); }
    }
  }

  const int crow = (wave >> 1) * 64 + (lane >> 4) * 4;
  const int ccol = (wave & 1) * 32 + (lane & 15);
  float dcol[2];
#pragma unroll
  for (int j = 0; j < 2; j++) dcol[j] = Dv[n0 + ccol + j * 16];
#pragma unroll
  for (int i = 0; i < 4; i++)
#pragma unroll
    for (int j = 0; j < 2; j++) {
      int col = n0 + ccol + j * 16;
#pragma unroll
      for (int g = 0; g < 4; g++) {
        int row = m0 + crow + i * 16 + g;
        out[(size_t)row * H + col] = acc[i][j][g] + dcol[j] * sig[(size_t)row * H + col];
      }
    }
#undef ISSUE_A2
#undef ISSUE_B2
}

// ---------------------------------------------------------------------------
// Launch
// ---------------------------------------------------------------------------
extern "C" void kernel_launch(void* const* d_in, const int* in_sizes, int n_in,
                              void* d_out, int out_size, void* d_ws, size_t ws_size,
                              hipStream_t stream) {
  const float* sig = (const float*)d_in[0];   // (L,H)
  const float* lam = (const float*)d_in[1];   // (P,2)
  const float* Bri = (const float*)d_in[2];   // (P,H,2)
  const float* Cri = (const float*)d_in[3];   // (H,P,2)
  const float* Dv  = (const float*)d_in[4];   // (H,)
  const float* lst = (const float*)d_in[5];   // (P,)
  float* out = (float*)d_out;

  unsigned short* Bcat = (unsigned short*)d_ws;             // N1*H bf16
  unsigned short* Ccat = Bcat + (size_t)N1 * H;             // H*N1 bf16
  unsigned short* Xl   = Ccat + (size_t)H * N1;             // L*N1 bf16 (x_local)
  float* powr = (float*)(Xl + (size_t)L * N1);              // T*P
  float* powi = powr + T * P;
  float* Sr   = powi + T * P;                               // P*NC (transposed)
  float* Si   = Sr + NC * P;
  float* car  = Si + NC * P;                                // NC*P
  float* cai  = car + NC * P;
  unsigned short* sigt = (unsigned short*)(cai + NC * P);   // L*H bf16, tile order
  unsigned short* Xg   = sigt + (size_t)L * H;              // L*N1 bf16, tile order

  k_prep<<<(2 * N1 * H + T * P + L * H / 8) / 256, 256, 0, stream>>>(
      sig, lam, lst, Bri, Cri, Bcat, Ccat, powr, powi, sigt);
  dim3 g1(L / 128, N1 / 128);
  k_gemm1s<<<g1, 256, 0, stream>>>(sigt, Bcat, lam, lst, Xl, Sr, Si);
  k_carry2<<<NC / 2, 64, 0, stream>>>(lam, lst, Sr, Si, car, cai);
  k_fix<<<L * 16 / 256, 256, 0, stream>>>(Xl, powr, powi, car, cai, Xg);
  dim3 g2(L / 128, H / 64);
  k_gemm2p<<<g2, 256, 0, stream>>>(Xg, Ccat, sig, Dv, out);
}